// Round 2
// 491.547 us; speedup vs baseline: 1.0143x; 1.0143x over previous
//
#include <hip/hip_runtime.h>

// WelfordEstimator: sequential Welford over batch dim B=32, per (s,h) position.
// x: (32, 2048, 1024) fp32. State: (2048,1024) mean/m2 fp32, nonzero int32, n scalar int.
// Output layout (all read back as fp32 by harness):
//   [0, B*SH)          : x passthrough
//   [B*SH, B*SH+SH)    : mean
//   [+SH, +2SH)        : m2
//   [+2SH, +3SH)       : nonzero (as float value — counts <= 32+n0, exact in fp32)
//   [B*SH+3SH]         : num_samples (as float value)
//
// R1: nontemporal hints on all streaming traffic (587 MB total, zero reuse —
//     18x the 32 MB aggregate L2, pure pollution otherwise) + 8-deep rolling
//     software prefetch with STATIC register names (runtime-indexed arrays
//     would spill to scratch). FP op sequence per element is IDENTICAL to the
//     verified bit-exact version.
// R2 fix: __builtin_nontemporal_* requires native vector types, not
//     HIP_vector_type<float,4> — use ext_vector_type(4) float (f32x4).

#define BATCH 32
#define SH  (2048LL * 1024LL)   // 2,097,152 positions
#define SH4 (SH / 4)            // f32x4 stride between consecutive batches

typedef float f32x4 __attribute__((ext_vector_type(4)));
typedef int   i32x4 __attribute__((ext_vector_type(4)));

__global__ __launch_bounds__(256) void welford_kernel(
    const float* __restrict__ x,
    const float* __restrict__ mean_in,
    const float* __restrict__ m2_in,
    const int*   __restrict__ nz_in,
    const int*   __restrict__ n_in,
    float* __restrict__ out)
{
    const long long tid = (long long)blockIdx.x * blockDim.x + threadIdx.x;
    const long long pos = tid * 4;          // 4 consecutive positions per thread
    if (pos >= SH) return;

    const f32x4* __restrict__ xin  = (const f32x4*)(x + pos);
    f32x4*       __restrict__ xout = (f32x4*)(out + pos);

    f32x4 mean = *(const f32x4*)(mean_in + pos);
    f32x4 m2   = *(const f32x4*)(m2_in   + pos);
    i32x4 nz   = *(const i32x4*)(nz_in   + pos);
    const int n0 = *n_in;

    float* __restrict__ out_mean = out + (long long)BATCH * SH;
    float* __restrict__ out_m2   = out_mean + SH;
    float* __restrict__ out_nz   = out_m2 + SH;

#define NT_LD(b) __builtin_nontemporal_load(xin + (b) * SH4)

    // One Welford step for one f32x4. Same op order/expressions as the
    // verified bit-exact version: nz, d = x - old_mean, mean += d*inv,
    // m2 += (x - new_mean)*d. inv shared across the 4 lanes.
#define STEP(b, r)                                                             \
    {                                                                          \
        __builtin_nontemporal_store((r), xout + (b) * SH4);                    \
        const float inv = 1.0f / (float)(n0 + (b) + 1);                        \
        nz[0] += ((r)[0] != 0.0f);                                             \
        { const float d = (r)[0] - mean[0]; mean[0] += d * inv;                \
          m2[0] += ((r)[0] - mean[0]) * d; }                                   \
        nz[1] += ((r)[1] != 0.0f);                                             \
        { const float d = (r)[1] - mean[1]; mean[1] += d * inv;                \
          m2[1] += ((r)[1] - mean[1]) * d; }                                   \
        nz[2] += ((r)[2] != 0.0f);                                             \
        { const float d = (r)[2] - mean[2]; mean[2] += d * inv;                \
          m2[2] += ((r)[2] - mean[2]) * d; }                                   \
        nz[3] += ((r)[3] != 0.0f);                                             \
        { const float d = (r)[3] - mean[3]; mean[3] += d * inv;                \
          m2[3] += ((r)[3] - mean[3]) * d; }                                   \
    }

    // 8-deep rolling prefetch, fully static register indexing.
    f32x4 r0 = NT_LD(0);
    f32x4 r1 = NT_LD(1);
    f32x4 r2 = NT_LD(2);
    f32x4 r3 = NT_LD(3);
    f32x4 r4 = NT_LD(4);
    f32x4 r5 = NT_LD(5);
    f32x4 r6 = NT_LD(6);
    f32x4 r7 = NT_LD(7);

    STEP(0,  r0); r0 = NT_LD(8);
    STEP(1,  r1); r1 = NT_LD(9);
    STEP(2,  r2); r2 = NT_LD(10);
    STEP(3,  r3); r3 = NT_LD(11);
    STEP(4,  r4); r4 = NT_LD(12);
    STEP(5,  r5); r5 = NT_LD(13);
    STEP(6,  r6); r6 = NT_LD(14);
    STEP(7,  r7); r7 = NT_LD(15);

    STEP(8,  r0); r0 = NT_LD(16);
    STEP(9,  r1); r1 = NT_LD(17);
    STEP(10, r2); r2 = NT_LD(18);
    STEP(11, r3); r3 = NT_LD(19);
    STEP(12, r4); r4 = NT_LD(20);
    STEP(13, r5); r5 = NT_LD(21);
    STEP(14, r6); r6 = NT_LD(22);
    STEP(15, r7); r7 = NT_LD(23);

    STEP(16, r0); r0 = NT_LD(24);
    STEP(17, r1); r1 = NT_LD(25);
    STEP(18, r2); r2 = NT_LD(26);
    STEP(19, r3); r3 = NT_LD(27);
    STEP(20, r4); r4 = NT_LD(28);
    STEP(21, r5); r5 = NT_LD(29);
    STEP(22, r6); r6 = NT_LD(30);
    STEP(23, r7); r7 = NT_LD(31);

    STEP(24, r0);
    STEP(25, r1);
    STEP(26, r2);
    STEP(27, r3);
    STEP(28, r4);
    STEP(29, r5);
    STEP(30, r6);
    STEP(31, r7);

#undef STEP
#undef NT_LD

    __builtin_nontemporal_store(mean, (f32x4*)(out_mean + pos));
    __builtin_nontemporal_store(m2,   (f32x4*)(out_m2   + pos));
    f32x4 nzf;
    nzf[0] = (float)nz[0]; nzf[1] = (float)nz[1];
    nzf[2] = (float)nz[2]; nzf[3] = (float)nz[3];
    __builtin_nontemporal_store(nzf,  (f32x4*)(out_nz   + pos));

    if (tid == 0) {
        out[(long long)(BATCH + 3) * SH] = (float)(n0 + BATCH);  // num_samples
    }
}

extern "C" void kernel_launch(void* const* d_in, const int* in_sizes, int n_in,
                              void* d_out, int out_size, void* d_ws, size_t ws_size,
                              hipStream_t stream) {
    const float* x    = (const float*)d_in[0];
    const float* mean = (const float*)d_in[1];
    const float* m2   = (const float*)d_in[2];
    const int*   nz   = (const int*)d_in[3];
    const int*   nsmp = (const int*)d_in[4];
    float* out = (float*)d_out;

    const long long n_threads = SH / 4;           // 524,288
    const int block = 256;
    const int grid = (int)((n_threads + block - 1) / block);  // 2048 blocks

    welford_kernel<<<grid, block, 0, stream>>>(x, mean, m2, nz, nsmp, out);
}